// Round 6
// baseline (142.497 us; speedup 1.0000x reference)
//
#include <hip/hip_runtime.h>
#include <hip/hip_fp16.h>

#define N_NODES 50000
#define N_EDGES 800000
#define D_FEAT  64
#define CAP     32                      // slots/node: 128B = 2 lines; P(deg>32)~1e-5
#define SPILL_CAP 262144                // 2 MB; input is Poisson(16) -> ~0 used
#define FILL_BLOCKS 2048                // 8 partitions x 256 blocks
#define PART_MAGIC 687195ull            // ceil(2^32 / 6250); exact for dst < 2^16

// ---------------------------------------------------------------------------
// Round 14: round-13 (pipelined fill + address-amortized pull) with ONE
//   change: hipMemsetAsync(cnt) replaced by zero_kernel. Hypothesis: graph-
//   captured memset nodes may lack the L2-invalidate barriers kernel->kernel
//   edges have on the 8 non-coherent XCD L2s -> stale cnt -> over-read of
//   stale csr slots in pull -> the observed one-edge-scale (6.04) replay
//   divergence. Kernel->kernel ordering closes that hole.
// ---------------------------------------------------------------------------

typedef float    fvec4 __attribute__((ext_vector_type(4)));
typedef unsigned uvec4 __attribute__((ext_vector_type(4)));

__device__ __forceinline__ unsigned pack_entry(unsigned s, float w) {
    return (s << 16) | (unsigned)__half_as_ushort(__float2half(w));
}
__device__ __forceinline__ float entry_w(unsigned e) {
    return __half2float(__ushort_as_half((unsigned short)(e & 0xffffu)));
}
__device__ __forceinline__ int part_of(int d) {
    return (int)(((unsigned long long)(unsigned)d * PART_MAGIC) >> 32);
}
__device__ __forceinline__ float2 h2f2(unsigned u) {
    __half2 h = *reinterpret_cast<__half2*>(&u);
    return __half22float2(h);
}

// queue fvec4 (elements 4t..4t+3 of linear fp32 queue) -> linear fp16 store.
__device__ __forceinline__ void conv_store(__half* __restrict__ qh, int t,
                                           const fvec4 q) {
    ushort4 h;
    h.x = __half_as_ushort(__float2half(q.x));
    h.y = __half_as_ushort(__float2half(q.y));
    h.z = __half_as_ushort(__float2half(q.z));
    h.w = __half_as_ushort(__float2half(q.w));
    reinterpret_cast<ushort4*>(qh)[t] = h;
}

__global__ void __launch_bounds__(256)
zero_kernel(int* __restrict__ cnt) {
    const int i = blockIdx.x * 256 + threadIdx.x;
    if (i <= N_NODES) cnt[i] = 0;      // i == N_NODES is spillcnt
}

#define PMASK(d) ((((part_of((d).x) == part) ? 1 : 0)) | \
                  (((part_of((d).y) == part) ? 2 : 0)) | \
                  (((part_of((d).z) == part) ? 4 : 0)) | \
                  (((part_of((d).w) == part) ? 8 : 0)))

#define DEP1(dd, ss, ww) do {                                                 \
        const int pos = atomicAdd(&cnt[(dd)], 1);                             \
        if (pos < CAP) {                                                      \
            csr[(size_t)(dd) * CAP + pos] =                                   \
                pack_entry((unsigned)(ss), (ww));                             \
        } else {                                                              \
            const int sp = atomicAdd(spillcnt, 1);                            \
            if (sp < SPILL_CAP)                                               \
                spill[sp] = make_uint2((unsigned)(ss) | ((unsigned)(dd) << 16),\
                                       __float_as_uint(ww));                  \
        } } while (0)

#define DEP4(m, d, s, wv) do { if (m) {                                       \
        if ((m) & 1) DEP1((d).x, (s).x, (wv).x);                              \
        if ((m) & 2) DEP1((d).y, (s).y, (wv).y);                              \
        if ((m) & 4) DEP1((d).z, (s).z, (wv).z);                              \
        if ((m) & 8) DEP1((d).w, (s).w, (wv).w); } } while (0)

__global__ void __launch_bounds__(256)
fill_kernel(const int* __restrict__ src, const int* __restrict__ dst,
            const float* __restrict__ weight, const float* __restrict__ queue,
            int* __restrict__ cnt, unsigned* __restrict__ csr,
            __half* __restrict__ qh, uint2* __restrict__ spill,
            int* __restrict__ spillcnt) {
    const int part = blockIdx.x & 7;              // XCD id (round-robin dispatch)
    const int bip  = blockIdx.x >> 3;
    const int nq   = N_EDGES / 4;                 // 200000 quads
    const int tstride = (FILL_BLOCKS / 8) * 256;  // 65536 threads/partition
    const int t0 = bip * 256 + threadIdx.x;       // < 65536

    const int4*   dq = reinterpret_cast<const int4*>(dst);
    const int4*   sq = reinterpret_cast<const int4*>(src);
    const float4* wq = reinterpret_cast<const float4*>(weight);

    // ---- phase A: ALL dst quad loads issued up front (independent) ----
    // k=0..2 always in-bounds: t0+131072 <= 196607 < 200000. k=3 iff t0<3392.
    const int4 d0 = dq[t0];
    const int4 d1 = dq[t0 + tstride];
    const int4 d2 = dq[t0 + 2 * tstride];
    const bool v3 = (t0 + 3 * tstride) < nq;
    int4 d3 = make_int4(-1, -1, -1, -1);          // part_of(-1) != any part
    if (v3) d3 = dq[t0 + 3 * tstride];

    // ---- convert iter 0 (streaming) hides dst latency ----
    const int gtid = blockIdx.x * 256 + threadIdx.x;     // < 524288
    const int CT = N_NODES * D_FEAT / 4;                 // 800000 ushort4s
    const fvec4 qa = __builtin_nontemporal_load(
        reinterpret_cast<const fvec4*>(queue) + gtid);
    conv_store(qh, gtid, qa);

    // ---- phase B: ownership masks; batched conditional src/w loads ----
    const int m0 = PMASK(d0), m1 = PMASK(d1), m2 = PMASK(d2), m3 = PMASK(d3);
    int4 s0, s1, s2, s3; float4 w0, w1, w2, w3;
    if (m0) { s0 = sq[t0];               w0 = wq[t0]; }
    if (m1) { s1 = sq[t0 + tstride];     w1 = wq[t0 + tstride]; }
    if (m2) { s2 = sq[t0 + 2 * tstride]; w2 = wq[t0 + 2 * tstride]; }
    if (m3) { s3 = sq[t0 + 3 * tstride]; w3 = wq[t0 + 3 * tstride]; }

    // ---- convert iter 1 hides src/weight latency ----
    const int t1c = gtid + FILL_BLOCKS * 256;            // +524288
    if (t1c < CT) {
        const fvec4 qb = __builtin_nontemporal_load(
            reinterpret_cast<const fvec4*>(queue) + t1c);
        conv_store(qh, t1c, qb);
    }

    // ---- phase C: batched deposits (atomics overlap across edges) ----
    DEP4(m0, d0, s0, w0);
    DEP4(m1, d1, s1, w1);
    DEP4(m2, d2, s2, w2);
    DEP4(m3, d3, s3, w3);
}

// One wave per node; 4 nodes per 256-thread block.
// Lane l: edge-group g = l>>3 (8 groups), chunk k = l&7 (16B of the 128B row).
// Group g handles slots {g, g+8, g+16, g+24}; one gather instr = 8 edges.
__global__ void __launch_bounds__(256)
pull_kernel(const __half* __restrict__ qh, const float* __restrict__ queue,
            const unsigned* __restrict__ csr, const int* __restrict__ cnt,
            const uint2* __restrict__ spill, const int* __restrict__ spillcnt,
            float* __restrict__ out) {
    const int node = blockIdx.x * 4 + (threadIdx.x >> 6);
    if (node >= N_NODES) return;                  // exact: 12500*4 = 50000
    const int lane = threadIdx.x & 63;
    const int g = lane >> 3;                      // edge group 0..7
    const int k = lane & 7;                       // 16B chunk within row

    const unsigned* p = csr + (size_t)node * CAP;
    const int c = min(cnt[node], CAP);            // wave-uniform
    const unsigned eown = p[lane & 31];           // whole entry list in-wave (128B)

    float a0 = 0, a1 = 0, a2 = 0, a3 = 0, a4 = 0, a5 = 0, a6 = 0, a7 = 0;

#pragma unroll
    for (int it = 0; it < 4; ++it) {
        if (it * 8 < c) {                         // wave-uniform tier skip
            const int slot = g + it * 8;          // 0..31
            unsigned e = __shfl(eown, slot);      // entry for this group's edge
            if (slot >= c) e = 0u;                // masked: src=0, w=fp16(0)
            const float w = entry_w(e);
            const uvec4 r = *reinterpret_cast<const uvec4*>(
                qh + (size_t)(e >> 16) * D_FEAT + k * 8);
            const float2 f0 = h2f2(r.x), f1 = h2f2(r.y),
                         f2 = h2f2(r.z), f3 = h2f2(r.w);
            a0 = fmaf(f0.x, w, a0);  a1 = fmaf(f0.y, w, a1);
            a2 = fmaf(f1.x, w, a2);  a3 = fmaf(f1.y, w, a3);
            a4 = fmaf(f2.x, w, a4);  a5 = fmaf(f2.y, w, a5);
            a6 = fmaf(f3.x, w, a6);  a7 = fmaf(f3.y, w, a7);
        }
    }

    // Cross-group reduce: groups differ in lane bits 3..5.
#pragma unroll
    for (int m = 8; m <= 32; m <<= 1) {
        a0 += __shfl_xor(a0, m);  a1 += __shfl_xor(a1, m);
        a2 += __shfl_xor(a2, m);  a3 += __shfl_xor(a3, m);
        a4 += __shfl_xor(a4, m);  a5 += __shfl_xor(a5, m);
        a6 += __shfl_xor(a6, m);  a7 += __shfl_xor(a7, m);
    }

    // Spill edges (normally zero). Lanes 0-7 hold final sums; add fp32 rows.
    const int nsp = min(*spillcnt, SPILL_CAP);
    if (nsp > 0 && lane < 8) {
        for (int t = 0; t < nsp; ++t) {
            const uint2 u = spill[t];
            if ((u.x >> 16) == (unsigned)node) {
                const float w = __uint_as_float(u.y);
                const float* qr = queue + (size_t)(u.x & 0xffffu) * D_FEAT + lane * 8;
                a0 = fmaf(qr[0], w, a0);  a1 = fmaf(qr[1], w, a1);
                a2 = fmaf(qr[2], w, a2);  a3 = fmaf(qr[3], w, a3);
                a4 = fmaf(qr[4], w, a4);  a5 = fmaf(qr[5], w, a5);
                a6 = fmaf(qr[6], w, a6);  a7 = fmaf(qr[7], w, a7);
            }
        }
    }

    if (lane < 8) {                               // 8 lanes x 32B = 256B row
        float* o = out + (size_t)node * D_FEAT + lane * 8;
        *reinterpret_cast<float4*>(o)     = make_float4(a0, a1, a2, a3);
        *reinterpret_cast<float4*>(o + 4) = make_float4(a4, a5, a6, a7);
    }
}

// --- Fallback (round-1 scatter) if ws_size is ever too small ---------------
__global__ void __launch_bounds__(256)
scatter_add_kernel(const float* __restrict__ queue,
                   const float* __restrict__ weight,
                   const int* __restrict__ src,
                   const int* __restrict__ dst,
                   float* __restrict__ out) {
    long long tid = (long long)blockIdx.x * blockDim.x + threadIdx.x;
    int e = (int)(tid >> 4);
    int c = ((int)tid & 15) << 2;
    if (e >= N_EDGES) return;
    int s = src[e], d = dst[e];
    float w = weight[e];
    const float4 q = *reinterpret_cast<const float4*>(queue + (size_t)s * D_FEAT + c);
    float* o = out + (size_t)d * D_FEAT + c;
    atomicAdd(o + 0, q.x * w);
    atomicAdd(o + 1, q.y * w);
    atomicAdd(o + 2, q.z * w);
    atomicAdd(o + 3, q.w * w);
}

extern "C" void kernel_launch(void* const* d_in, const int* in_sizes, int n_in,
                              void* d_out, int out_size, void* d_ws, size_t ws_size,
                              hipStream_t stream) {
    const float* queue  = (const float*)d_in[0];
    const float* weight = (const float*)d_in[1];
    const int*   src    = (const int*)d_in[2];
    const int*   dst    = (const int*)d_in[3];
    float* out = (float*)d_out;

    // Workspace layout (16B-aligned blocks):
    //   csr:      N_NODES*CAP unsigned   (6.4 MB)
    //   qh:       N_NODES*D_FEAT __half  (6.4 MB)
    //   spill:    SPILL_CAP uint2        (2 MB)
    //   cnt:      N_NODES int   \ zeroed by zero_kernel
    //   spillcnt: 1 int         /
    const size_t csr_bytes   = (size_t)N_NODES * CAP * sizeof(unsigned);
    const size_t qh_bytes    = (size_t)N_NODES * D_FEAT * sizeof(__half);
    const size_t spill_bytes = (size_t)SPILL_CAP * sizeof(uint2);
    const size_t need = csr_bytes + qh_bytes + spill_bytes
                      + (size_t)(N_NODES + 1) * sizeof(int);

    if (ws_size < need) {  // safety fallback: round-1 scatter path
        hipMemsetAsync(out, 0, (size_t)out_size * sizeof(float), stream);
        const long long total = (long long)N_EDGES * 16;
        scatter_add_kernel<<<(int)((total + 255) / 256), 256, 0, stream>>>(
            queue, weight, src, dst, out);
        return;
    }

    char* ws = (char*)d_ws;
    unsigned* csr = (unsigned*)ws;
    __half* qh    = (__half*)(ws + csr_bytes);
    uint2* spill  = (uint2*)(ws + csr_bytes + qh_bytes);
    int* cnt      = (int*)(ws + csr_bytes + qh_bytes + spill_bytes);
    int* spillcnt = cnt + N_NODES;

    zero_kernel<<<(N_NODES + 256) / 256, 256, 0, stream>>>(cnt);

    fill_kernel<<<FILL_BLOCKS, 256, 0, stream>>>(
        src, dst, weight, queue, cnt, csr, qh, spill, spillcnt);
    pull_kernel<<<(N_NODES + 3) / 4, 256, 0, stream>>>(
        qh, queue, csr, cnt, spill, spillcnt, out);
}

// Round 7
// 129.267 us; speedup vs baseline: 1.1024x; 1.1024x over previous
//
#include <hip/hip_runtime.h>
#include <hip/hip_fp16.h>

#define N_NODES 50000
#define N_EDGES 800000
#define D_FEAT  64
#define CAP     32                      // csr slots/node; P(deg>32)~1e-5 -> spill
#define SPILL_CAP 262144                // 2 MB; ~0 used in practice
#define NBUCK   196                     // dst buckets of 256 nodes: (50000+255)>>8
#define BUCK_CAP 5120                   // edges/bucket cap: Poisson(4096), 16 sigma
#define BIN_BLOCKS 256                  // pass-1 blocks; 3125 edges each
#define EPB     (N_EDGES / BIN_BLOCKS)  // 3125

// ---------------------------------------------------------------------------
// Round 15: fill's 800k device-scope returning atomics (~1/cy/XCD fabric port
//   = the measured 44-47us floor, insensitive to load pipelining per r6) are
//   replaced by two-level binning:
//   pass1 bin_kernel: per-block LDS histogram over 196 dst-buckets -> ONE
//     global atomicAdd per (block,bucket) reserve (~50k atomics, was 800k)
//     -> clustered scatter of (src,nlo,w) records into per-bucket regions.
//     queue fp32->fp16 convert fused at the end (streaming).
//   pass2 csr_kernel: one block per bucket; LDS-atomic per-node positioning
//     (global-atomic-free), CAP-bounded csr writes, exact cnt written
//     coalesced (cnt needs no zeroing). Overflow -> spill at every stage.
//   pull: round-3 address-amortized gather (known ~27us), unchanged.
// ---------------------------------------------------------------------------

typedef unsigned uvec4 __attribute__((ext_vector_type(4)));

__device__ __forceinline__ unsigned pack_entry(unsigned s, float w) {
    return (s << 16) | (unsigned)__half_as_ushort(__float2half(w));
}
__device__ __forceinline__ float entry_w(unsigned e) {
    return __half2float(__ushort_as_half((unsigned short)(e & 0xffffu)));
}
__device__ __forceinline__ float2 h2f2(unsigned u) {
    __half2 h = *reinterpret_cast<__half2*>(&u);
    return __half22float2(h);
}

__global__ void __launch_bounds__(256)
init_kernel(int* __restrict__ gbase, int* __restrict__ spillcnt) {
    const int i = threadIdx.x;                    // single block
    if (i < NBUCK) gbase[i] = i * BUCK_CAP;
    if (i == 0) *spillcnt = 0;
}

// Pass 1: bucket-bin edges + fused queue convert.
__global__ void __launch_bounds__(256)
bin_kernel(const int* __restrict__ src, const int* __restrict__ dst,
           const float* __restrict__ weight, const float* __restrict__ queue,
           int* __restrict__ gbase, uint2* __restrict__ ebuf,
           __half* __restrict__ qh, uint2* __restrict__ spill,
           int* __restrict__ spillcnt) {
    __shared__ unsigned hist[256];
    __shared__ unsigned cursor[256];
    const int tid = threadIdx.x;
    const int eb  = blockIdx.x * EPB;             // this block's edge chunk

    hist[tid] = 0;
    __syncthreads();

    for (int i = tid; i < EPB; i += 256)          // LDS histogram (13 iters)
        atomicAdd(&hist[(unsigned)dst[eb + i] >> 8], 1u);
    __syncthreads();

    if (tid < NBUCK && hist[tid] > 0)             // one reserve per (block,bucket)
        cursor[tid] = (unsigned)atomicAdd(&gbase[tid], (int)hist[tid]);
    __syncthreads();

    for (int i = tid; i < EPB; i += 256) {        // clustered scatter
        const int e = eb + i;
        const int d = dst[e];
        const unsigned b = (unsigned)d >> 8;
        const unsigned pos = atomicAdd(&cursor[b], 1u);   // global position
        const int   s = src[e];
        const float w = weight[e];
        if (pos < (b + 1) * BUCK_CAP) {
            ebuf[pos] = make_uint2((unsigned)s | ((unsigned)(d & 255) << 16),
                                   __float_as_uint(w));
        } else {                                  // bucket overflow (never, 16σ)
            const int sp = atomicAdd(spillcnt, 1);
            if (sp < SPILL_CAP)
                spill[sp] = make_uint2((unsigned)s | ((unsigned)d << 16),
                                       __float_as_uint(w));
        }
    }

    // Fused queue fp32 -> fp16 convert (streams under the scatter drain).
    const int gid = blockIdx.x * 256 + tid;       // 65536 threads
    for (int t = gid; t < N_NODES * D_FEAT / 4; t += BIN_BLOCKS * 256) {
        const float4 q = reinterpret_cast<const float4*>(queue)[t];
        ushort4 h;
        h.x = __half_as_ushort(__float2half(q.x));
        h.y = __half_as_ushort(__float2half(q.y));
        h.z = __half_as_ushort(__float2half(q.z));
        h.w = __half_as_ushort(__float2half(q.w));
        reinterpret_cast<ushort4*>(qh)[t] = h;
    }
}

// Pass 2: one block per bucket; LDS-atomic per-node CSR build, exact cnt.
__global__ void __launch_bounds__(256)
csr_kernel(const uint2* __restrict__ ebuf, const int* __restrict__ gbase,
           unsigned* __restrict__ csr, int* __restrict__ cnt,
           uint2* __restrict__ spill, int* __restrict__ spillcnt) {
    __shared__ unsigned lcnt[256];
    const int b   = blockIdx.x;                   // 0..195
    const int tid = threadIdx.x;
    lcnt[tid] = 0;
    __syncthreads();

    const int ebase = b * BUCK_CAP;
    const int total = min(gbase[b] - ebase, BUCK_CAP);  // final cursor - start

    for (int i = tid; i < total; i += 256) {
        const uint2 u = ebuf[ebase + i];
        const unsigned nlo  = u.x >> 16;
        const unsigned node = ((unsigned)b << 8) + nlo;
        const unsigned pos  = atomicAdd(&lcnt[nlo], 1u);    // LDS atomic
        if (pos < CAP) {
            csr[(size_t)node * CAP + pos] =
                pack_entry(u.x & 0xffffu, __uint_as_float(u.y));
        } else {                                  // deg > 32: spill (fp32 path)
            const int sp = atomicAdd(spillcnt, 1);
            if (sp < SPILL_CAP)
                spill[sp] = make_uint2((u.x & 0xffffu) | (node << 16), u.y);
        }
    }
    __syncthreads();

    const unsigned node = ((unsigned)b << 8) + tid;
    if (node < N_NODES) cnt[node] = (int)min(lcnt[tid], (unsigned)CAP);
}

// One wave per node; 4 nodes per 256-thread block. (round-3, unchanged)
// Lane l: edge-group g = l>>3 (8 groups), chunk k = l&7 (16B of the 128B row).
// Group g handles slots {g, g+8, g+16, g+24}; one gather instr = 8 edges.
__global__ void __launch_bounds__(256)
pull_kernel(const __half* __restrict__ qh, const float* __restrict__ queue,
            const unsigned* __restrict__ csr, const int* __restrict__ cnt,
            const uint2* __restrict__ spill, const int* __restrict__ spillcnt,
            float* __restrict__ out) {
    const int node = blockIdx.x * 4 + (threadIdx.x >> 6);
    if (node >= N_NODES) return;                  // exact: 12500*4 = 50000
    const int lane = threadIdx.x & 63;
    const int g = lane >> 3;                      // edge group 0..7
    const int k = lane & 7;                       // 16B chunk within row

    const unsigned* p = csr + (size_t)node * CAP;
    const int c = min(cnt[node], CAP);            // wave-uniform
    const unsigned eown = p[lane & 31];           // whole entry list in-wave (128B)

    float a0 = 0, a1 = 0, a2 = 0, a3 = 0, a4 = 0, a5 = 0, a6 = 0, a7 = 0;

#pragma unroll
    for (int it = 0; it < 4; ++it) {
        if (it * 8 < c) {                         // wave-uniform tier skip
            const int slot = g + it * 8;          // 0..31
            unsigned e = __shfl(eown, slot);      // entry for this group's edge
            if (slot >= c) e = 0u;                // masked: src=0, w=fp16(0)
            const float w = entry_w(e);
            const uvec4 r = *reinterpret_cast<const uvec4*>(
                qh + (size_t)(e >> 16) * D_FEAT + k * 8);
            const float2 f0 = h2f2(r.x), f1 = h2f2(r.y),
                         f2 = h2f2(r.z), f3 = h2f2(r.w);
            a0 = fmaf(f0.x, w, a0);  a1 = fmaf(f0.y, w, a1);
            a2 = fmaf(f1.x, w, a2);  a3 = fmaf(f1.y, w, a3);
            a4 = fmaf(f2.x, w, a4);  a5 = fmaf(f2.y, w, a5);
            a6 = fmaf(f3.x, w, a6);  a7 = fmaf(f3.y, w, a7);
        }
    }

    // Cross-group reduce: groups differ in lane bits 3..5.
#pragma unroll
    for (int m = 8; m <= 32; m <<= 1) {
        a0 += __shfl_xor(a0, m);  a1 += __shfl_xor(a1, m);
        a2 += __shfl_xor(a2, m);  a3 += __shfl_xor(a3, m);
        a4 += __shfl_xor(a4, m);  a5 += __shfl_xor(a5, m);
        a6 += __shfl_xor(a6, m);  a7 += __shfl_xor(a7, m);
    }

    // Spill edges (normally zero). Lanes 0-7 hold final sums; add fp32 rows.
    const int nsp = min(*spillcnt, SPILL_CAP);
    if (nsp > 0 && lane < 8) {
        for (int t = 0; t < nsp; ++t) {
            const uint2 u = spill[t];
            if ((u.x >> 16) == (unsigned)node) {
                const float w = __uint_as_float(u.y);
                const float* qr = queue + (size_t)(u.x & 0xffffu) * D_FEAT + lane * 8;
                a0 = fmaf(qr[0], w, a0);  a1 = fmaf(qr[1], w, a1);
                a2 = fmaf(qr[2], w, a2);  a3 = fmaf(qr[3], w, a3);
                a4 = fmaf(qr[4], w, a4);  a5 = fmaf(qr[5], w, a5);
                a6 = fmaf(qr[6], w, a6);  a7 = fmaf(qr[7], w, a7);
            }
        }
    }

    if (lane < 8) {                               // 8 lanes x 32B = 256B row
        float* o = out + (size_t)node * D_FEAT + lane * 8;
        *reinterpret_cast<float4*>(o)     = make_float4(a0, a1, a2, a3);
        *reinterpret_cast<float4*>(o + 4) = make_float4(a4, a5, a6, a7);
    }
}

// --- Fallback (round-1 scatter) if ws_size is ever too small ---------------
__global__ void __launch_bounds__(256)
scatter_add_kernel(const float* __restrict__ queue,
                   const float* __restrict__ weight,
                   const int* __restrict__ src,
                   const int* __restrict__ dst,
                   float* __restrict__ out) {
    long long tid = (long long)blockIdx.x * blockDim.x + threadIdx.x;
    int e = (int)(tid >> 4);
    int c = ((int)tid & 15) << 2;
    if (e >= N_EDGES) return;
    int s = src[e], d = dst[e];
    float w = weight[e];
    const float4 q = *reinterpret_cast<const float4*>(queue + (size_t)s * D_FEAT + c);
    float* o = out + (size_t)d * D_FEAT + c;
    atomicAdd(o + 0, q.x * w);
    atomicAdd(o + 1, q.y * w);
    atomicAdd(o + 2, q.z * w);
    atomicAdd(o + 3, q.w * w);
}

extern "C" void kernel_launch(void* const* d_in, const int* in_sizes, int n_in,
                              void* d_out, int out_size, void* d_ws, size_t ws_size,
                              hipStream_t stream) {
    const float* queue  = (const float*)d_in[0];
    const float* weight = (const float*)d_in[1];
    const int*   src    = (const int*)d_in[2];
    const int*   dst    = (const int*)d_in[3];
    float* out = (float*)d_out;

    // Workspace layout (16B-aligned blocks):
    //   csr:   N_NODES*CAP unsigned     (6.4 MB)
    //   qh:    N_NODES*D_FEAT __half    (6.4 MB)
    //   ebuf:  NBUCK*BUCK_CAP uint2     (8.0 MB)
    //   spill: SPILL_CAP uint2          (2 MB)
    //   cnt:   N_NODES int              (written in full by csr_kernel)
    //   gbase: NBUCK int + spillcnt     (init_kernel)
    const size_t csr_bytes   = (size_t)N_NODES * CAP * sizeof(unsigned);
    const size_t qh_bytes    = (size_t)N_NODES * D_FEAT * sizeof(__half);
    const size_t ebuf_bytes  = (size_t)NBUCK * BUCK_CAP * sizeof(uint2);
    const size_t spill_bytes = (size_t)SPILL_CAP * sizeof(uint2);
    const size_t cnt_bytes   = (size_t)N_NODES * sizeof(int);
    const size_t need = csr_bytes + qh_bytes + ebuf_bytes + spill_bytes
                      + cnt_bytes + (size_t)(NBUCK + 1) * sizeof(int);

    if (ws_size < need) {  // safety fallback: round-1 scatter path
        hipMemsetAsync(out, 0, (size_t)out_size * sizeof(float), stream);
        const long long total = (long long)N_EDGES * 16;
        scatter_add_kernel<<<(int)((total + 255) / 256), 256, 0, stream>>>(
            queue, weight, src, dst, out);
        return;
    }

    char* ws = (char*)d_ws;
    unsigned* csr  = (unsigned*)ws;
    __half* qh     = (__half*)(ws + csr_bytes);
    uint2* ebuf    = (uint2*)(ws + csr_bytes + qh_bytes);
    uint2* spill   = (uint2*)(ws + csr_bytes + qh_bytes + ebuf_bytes);
    int* cnt       = (int*)(ws + csr_bytes + qh_bytes + ebuf_bytes + spill_bytes);
    int* gbase     = cnt + N_NODES;
    int* spillcnt  = gbase + NBUCK;

    init_kernel<<<1, 256, 0, stream>>>(gbase, spillcnt);
    bin_kernel<<<BIN_BLOCKS, 256, 0, stream>>>(
        src, dst, weight, queue, gbase, ebuf, qh, spill, spillcnt);
    csr_kernel<<<NBUCK, 256, 0, stream>>>(
        ebuf, gbase, csr, cnt, spill, spillcnt);
    pull_kernel<<<(N_NODES + 3) / 4, 256, 0, stream>>>(
        qh, queue, csr, cnt, spill, spillcnt, out);
}

// Round 8
// 118.751 us; speedup vs baseline: 1.2000x; 1.0886x over previous
//
#include <hip/hip_runtime.h>
#include <hip/hip_fp16.h>

#define N_NODES 50000
#define N_EDGES 800000
#define D_FEAT  64
#define CAP     32                      // csr slots/node; P(deg>32)~1e-5 -> spill
#define SPILL_CAP 262144                // 2 MB; ~0 used in practice
#define NBUCK   196                     // dst buckets of 256 nodes: (50000+255)>>8
#define BUCK_CAP 5120                   // edges/bucket cap: Poisson(4096), 16 sigma
#define BIN_BLOCKS 256                  // pass-1 blocks; 3125 edges each
#define EPB     (N_EDGES / BIN_BLOCKS)  // 3125
#define BIN_T   1024                    // pass-1/2 block size: 16 waves/CU

// ---------------------------------------------------------------------------
// Round 16: round-15 binning pipeline with the occupancy fixed. r15 measured
//   bin+csr ~= 33us at 1 wave/SIMD (256x256 / 196x256 grids): latency-bound,
//   13-16 serial load->atomic->store iterations per thread. This round keeps
//   ALL atomic counts identical (50k reserves, LDS elsewhere) but runs the
//   same 256 / 196 blocks at 1024 threads: 16 waves/CU, ~3-4 iterations.
//   pull: round-3 address-amortized gather (known ~3us), unchanged.
// ---------------------------------------------------------------------------

typedef unsigned uvec4 __attribute__((ext_vector_type(4)));

__device__ __forceinline__ unsigned pack_entry(unsigned s, float w) {
    return (s << 16) | (unsigned)__half_as_ushort(__float2half(w));
}
__device__ __forceinline__ float entry_w(unsigned e) {
    return __half2float(__ushort_as_half((unsigned short)(e & 0xffffu)));
}
__device__ __forceinline__ float2 h2f2(unsigned u) {
    __half2 h = *reinterpret_cast<__half2*>(&u);
    return __half22float2(h);
}

__global__ void __launch_bounds__(256)
init_kernel(int* __restrict__ gbase, int* __restrict__ spillcnt) {
    const int i = threadIdx.x;                    // single block
    if (i < NBUCK) gbase[i] = i * BUCK_CAP;
    if (i == 0) *spillcnt = 0;
}

// Pass 1: bucket-bin edges + fused queue convert.
__global__ void __launch_bounds__(BIN_T)
bin_kernel(const int* __restrict__ src, const int* __restrict__ dst,
           const float* __restrict__ weight, const float* __restrict__ queue,
           int* __restrict__ gbase, uint2* __restrict__ ebuf,
           __half* __restrict__ qh, uint2* __restrict__ spill,
           int* __restrict__ spillcnt) {
    __shared__ unsigned hist[256];
    __shared__ unsigned cursor[256];
    const int tid = threadIdx.x;
    const int eb  = blockIdx.x * EPB;             // this block's edge chunk

    if (tid < 256) hist[tid] = 0;
    __syncthreads();

    for (int i = tid; i < EPB; i += BIN_T)        // LDS histogram (~3 iters)
        atomicAdd(&hist[(unsigned)dst[eb + i] >> 8], 1u);
    __syncthreads();

    if (tid < NBUCK && hist[tid] > 0)             // one reserve per (block,bucket)
        cursor[tid] = (unsigned)atomicAdd(&gbase[tid], (int)hist[tid]);
    __syncthreads();

    for (int i = tid; i < EPB; i += BIN_T) {      // clustered scatter (~3 iters)
        const int e = eb + i;
        const int d = dst[e];
        const unsigned b = (unsigned)d >> 8;
        const unsigned pos = atomicAdd(&cursor[b], 1u);   // global position
        const int   s = src[e];
        const float w = weight[e];
        if (pos < (b + 1) * BUCK_CAP) {
            ebuf[pos] = make_uint2((unsigned)s | ((unsigned)(d & 255) << 16),
                                   __float_as_uint(w));
        } else {                                  // bucket overflow (never, 16σ)
            const int sp = atomicAdd(spillcnt, 1);
            if (sp < SPILL_CAP)
                spill[sp] = make_uint2((unsigned)s | ((unsigned)d << 16),
                                       __float_as_uint(w));
        }
    }

    // Fused queue fp32 -> fp16 convert (~3 iterations, streams).
    const int gid = blockIdx.x * BIN_T + tid;     // 262144 threads
    for (int t = gid; t < N_NODES * D_FEAT / 4; t += BIN_BLOCKS * BIN_T) {
        const float4 q = reinterpret_cast<const float4*>(queue)[t];
        ushort4 h;
        h.x = __half_as_ushort(__float2half(q.x));
        h.y = __half_as_ushort(__float2half(q.y));
        h.z = __half_as_ushort(__float2half(q.z));
        h.w = __half_as_ushort(__float2half(q.w));
        reinterpret_cast<ushort4*>(qh)[t] = h;
    }
}

// Pass 2: one block per bucket; LDS-atomic per-node CSR build, exact cnt.
__global__ void __launch_bounds__(BIN_T)
csr_kernel(const uint2* __restrict__ ebuf, const int* __restrict__ gbase,
           unsigned* __restrict__ csr, int* __restrict__ cnt,
           uint2* __restrict__ spill, int* __restrict__ spillcnt) {
    __shared__ unsigned lcnt[256];
    const int b   = blockIdx.x;                   // 0..195
    const int tid = threadIdx.x;
    if (tid < 256) lcnt[tid] = 0;
    __syncthreads();

    const int ebase = b * BUCK_CAP;
    const int total = min(gbase[b] - ebase, BUCK_CAP);  // final cursor - start

    for (int i = tid; i < total; i += BIN_T) {    // ~4 iterations
        const uint2 u = ebuf[ebase + i];
        const unsigned nlo  = u.x >> 16;
        const unsigned node = ((unsigned)b << 8) + nlo;
        const unsigned pos  = atomicAdd(&lcnt[nlo], 1u);    // LDS atomic
        if (pos < CAP) {
            csr[(size_t)node * CAP + pos] =
                pack_entry(u.x & 0xffffu, __uint_as_float(u.y));
        } else {                                  // deg > 32: spill (fp32 path)
            const int sp = atomicAdd(spillcnt, 1);
            if (sp < SPILL_CAP)
                spill[sp] = make_uint2((u.x & 0xffffu) | (node << 16), u.y);
        }
    }
    __syncthreads();

    if (tid < 256) {
        const unsigned node = ((unsigned)b << 8) + tid;
        if (node < N_NODES) cnt[node] = (int)min(lcnt[tid], (unsigned)CAP);
    }
}

// One wave per node; 4 nodes per 256-thread block. (round-3, unchanged)
// Lane l: edge-group g = l>>3 (8 groups), chunk k = l&7 (16B of the 128B row).
// Group g handles slots {g, g+8, g+16, g+24}; one gather instr = 8 edges.
__global__ void __launch_bounds__(256)
pull_kernel(const __half* __restrict__ qh, const float* __restrict__ queue,
            const unsigned* __restrict__ csr, const int* __restrict__ cnt,
            const uint2* __restrict__ spill, const int* __restrict__ spillcnt,
            float* __restrict__ out) {
    const int node = blockIdx.x * 4 + (threadIdx.x >> 6);
    if (node >= N_NODES) return;                  // exact: 12500*4 = 50000
    const int lane = threadIdx.x & 63;
    const int g = lane >> 3;                      // edge group 0..7
    const int k = lane & 7;                       // 16B chunk within row

    const unsigned* p = csr + (size_t)node * CAP;
    const int c = min(cnt[node], CAP);            // wave-uniform
    const unsigned eown = p[lane & 31];           // whole entry list in-wave (128B)

    float a0 = 0, a1 = 0, a2 = 0, a3 = 0, a4 = 0, a5 = 0, a6 = 0, a7 = 0;

#pragma unroll
    for (int it = 0; it < 4; ++it) {
        if (it * 8 < c) {                         // wave-uniform tier skip
            const int slot = g + it * 8;          // 0..31
            unsigned e = __shfl(eown, slot);      // entry for this group's edge
            if (slot >= c) e = 0u;                // masked: src=0, w=fp16(0)
            const float w = entry_w(e);
            const uvec4 r = *reinterpret_cast<const uvec4*>(
                qh + (size_t)(e >> 16) * D_FEAT + k * 8);
            const float2 f0 = h2f2(r.x), f1 = h2f2(r.y),
                         f2 = h2f2(r.z), f3 = h2f2(r.w);
            a0 = fmaf(f0.x, w, a0);  a1 = fmaf(f0.y, w, a1);
            a2 = fmaf(f1.x, w, a2);  a3 = fmaf(f1.y, w, a3);
            a4 = fmaf(f2.x, w, a4);  a5 = fmaf(f2.y, w, a5);
            a6 = fmaf(f3.x, w, a6);  a7 = fmaf(f3.y, w, a7);
        }
    }

    // Cross-group reduce: groups differ in lane bits 3..5.
#pragma unroll
    for (int m = 8; m <= 32; m <<= 1) {
        a0 += __shfl_xor(a0, m);  a1 += __shfl_xor(a1, m);
        a2 += __shfl_xor(a2, m);  a3 += __shfl_xor(a3, m);
        a4 += __shfl_xor(a4, m);  a5 += __shfl_xor(a5, m);
        a6 += __shfl_xor(a6, m);  a7 += __shfl_xor(a7, m);
    }

    // Spill edges (normally zero). Lanes 0-7 hold final sums; add fp32 rows.
    const int nsp = min(*spillcnt, SPILL_CAP);
    if (nsp > 0 && lane < 8) {
        for (int t = 0; t < nsp; ++t) {
            const uint2 u = spill[t];
            if ((u.x >> 16) == (unsigned)node) {
                const float w = __uint_as_float(u.y);
                const float* qr = queue + (size_t)(u.x & 0xffffu) * D_FEAT + lane * 8;
                a0 = fmaf(qr[0], w, a0);  a1 = fmaf(qr[1], w, a1);
                a2 = fmaf(qr[2], w, a2);  a3 = fmaf(qr[3], w, a3);
                a4 = fmaf(qr[4], w, a4);  a5 = fmaf(qr[5], w, a5);
                a6 = fmaf(qr[6], w, a6);  a7 = fmaf(qr[7], w, a7);
            }
        }
    }

    if (lane < 8) {                               // 8 lanes x 32B = 256B row
        float* o = out + (size_t)node * D_FEAT + lane * 8;
        *reinterpret_cast<float4*>(o)     = make_float4(a0, a1, a2, a3);
        *reinterpret_cast<float4*>(o + 4) = make_float4(a4, a5, a6, a7);
    }
}

// --- Fallback (round-1 scatter) if ws_size is ever too small ---------------
__global__ void __launch_bounds__(256)
scatter_add_kernel(const float* __restrict__ queue,
                   const float* __restrict__ weight,
                   const int* __restrict__ src,
                   const int* __restrict__ dst,
                   float* __restrict__ out) {
    long long tid = (long long)blockIdx.x * blockDim.x + threadIdx.x;
    int e = (int)(tid >> 4);
    int c = ((int)tid & 15) << 2;
    if (e >= N_EDGES) return;
    int s = src[e], d = dst[e];
    float w = weight[e];
    const float4 q = *reinterpret_cast<const float4*>(queue + (size_t)s * D_FEAT + c);
    float* o = out + (size_t)d * D_FEAT + c;
    atomicAdd(o + 0, q.x * w);
    atomicAdd(o + 1, q.y * w);
    atomicAdd(o + 2, q.z * w);
    atomicAdd(o + 3, q.w * w);
}

extern "C" void kernel_launch(void* const* d_in, const int* in_sizes, int n_in,
                              void* d_out, int out_size, void* d_ws, size_t ws_size,
                              hipStream_t stream) {
    const float* queue  = (const float*)d_in[0];
    const float* weight = (const float*)d_in[1];
    const int*   src    = (const int*)d_in[2];
    const int*   dst    = (const int*)d_in[3];
    float* out = (float*)d_out;

    // Workspace layout (16B-aligned blocks):
    //   csr:   N_NODES*CAP unsigned     (6.4 MB)
    //   qh:    N_NODES*D_FEAT __half    (6.4 MB)
    //   ebuf:  NBUCK*BUCK_CAP uint2     (8.0 MB)
    //   spill: SPILL_CAP uint2          (2 MB)
    //   cnt:   N_NODES int              (written in full by csr_kernel)
    //   gbase: NBUCK int + spillcnt     (init_kernel)
    const size_t csr_bytes   = (size_t)N_NODES * CAP * sizeof(unsigned);
    const size_t qh_bytes    = (size_t)N_NODES * D_FEAT * sizeof(__half);
    const size_t ebuf_bytes  = (size_t)NBUCK * BUCK_CAP * sizeof(uint2);
    const size_t spill_bytes = (size_t)SPILL_CAP * sizeof(uint2);
    const size_t cnt_bytes   = (size_t)N_NODES * sizeof(int);
    const size_t need = csr_bytes + qh_bytes + ebuf_bytes + spill_bytes
                      + cnt_bytes + (size_t)(NBUCK + 1) * sizeof(int);

    if (ws_size < need) {  // safety fallback: round-1 scatter path
        hipMemsetAsync(out, 0, (size_t)out_size * sizeof(float), stream);
        const long long total = (long long)N_EDGES * 16;
        scatter_add_kernel<<<(int)((total + 255) / 256), 256, 0, stream>>>(
            queue, weight, src, dst, out);
        return;
    }

    char* ws = (char*)d_ws;
    unsigned* csr  = (unsigned*)ws;
    __half* qh     = (__half*)(ws + csr_bytes);
    uint2* ebuf    = (uint2*)(ws + csr_bytes + qh_bytes);
    uint2* spill   = (uint2*)(ws + csr_bytes + qh_bytes + ebuf_bytes);
    int* cnt       = (int*)(ws + csr_bytes + qh_bytes + ebuf_bytes + spill_bytes);
    int* gbase     = cnt + N_NODES;
    int* spillcnt  = gbase + NBUCK;

    init_kernel<<<1, 256, 0, stream>>>(gbase, spillcnt);
    bin_kernel<<<BIN_BLOCKS, BIN_T, 0, stream>>>(
        src, dst, weight, queue, gbase, ebuf, qh, spill, spillcnt);
    csr_kernel<<<NBUCK, BIN_T, 0, stream>>>(
        ebuf, gbase, csr, cnt, spill, spillcnt);
    pull_kernel<<<(N_NODES + 3) / 4, 256, 0, stream>>>(
        qh, queue, csr, cnt, spill, spillcnt, out);
}

// Round 9
// 117.873 us; speedup vs baseline: 1.2089x; 1.0074x over previous
//
#include <hip/hip_runtime.h>
#include <hip/hip_fp16.h>

#define N_NODES 50000
#define N_EDGES 800000
#define D_FEAT  64
#define CAP     32                      // csr slots/node; deg>32 -> oflow (fp32)
#define NBUCK   196                     // dst buckets of 256 nodes
#define BIN_BLOCKS 256
#define EPB     (N_EDGES / BIN_BLOCKS)  // 3125
#define SLICE_CAP 64                    // edges per (bucket,block) slice; lambda=15.9
#define SPB     256                     // per-block spill slots (slice overflow, ~never)
#define OFC     128                     // per-bucket LDS overflow list (deg>32 excess)

// ---------------------------------------------------------------------------
// Round 17: static-slice binning + LDS-resident CSR. vs r16:
//   - ebuf[bucket][block][64] slices are STATIC: no init kernel, no global
//     reserve atomics, no histogram pass (dst read once). Headers hcnt/scnt
//     written unconditionally every call -> zero pre-initialization anywhere.
//   - gather = csr+pull fused: bucket CSR built in 32KB LDS and consumed in
//     place; the 10MB csr/cnt HBM round-trip and one launch are gone.
//   - 4 kernels -> 2. Spill safety: slice overflow -> per-block spillbuf
//     (headers scanned by gather); deg>32 -> in-LDS fp32 oflow list.
// ---------------------------------------------------------------------------

typedef unsigned uvec4 __attribute__((ext_vector_type(4)));

__device__ __forceinline__ unsigned pack_entry(unsigned s, float w) {
    return (s << 16) | (unsigned)__half_as_ushort(__float2half(w));
}
__device__ __forceinline__ float entry_w(unsigned e) {
    return __half2float(__ushort_as_half((unsigned short)(e & 0xffffu)));
}
__device__ __forceinline__ float2 h2f2(unsigned u) {
    __half2 h = *reinterpret_cast<__half2*>(&u);
    return __half22float2(h);
}

// Pass 1: scatter edges into static (bucket,block) slices + fused convert.
__global__ void __launch_bounds__(1024)
bin_kernel(const int* __restrict__ src, const int* __restrict__ dst,
           const float* __restrict__ weight, const float* __restrict__ queue,
           uint2* __restrict__ ebuf, unsigned* __restrict__ hcnt,
           unsigned* __restrict__ scnt, uint2* __restrict__ spillbuf,
           __half* __restrict__ qh) {
    __shared__ unsigned lcur[NBUCK];
    __shared__ unsigned lsp;
    const int tid = threadIdx.x;
    const int bi  = blockIdx.x;
    if (tid < NBUCK) lcur[tid] = 0;
    if (tid == 0) lsp = 0;
    __syncthreads();

    const int eb = bi * EPB;
    for (int i = tid; i < EPB; i += 1024) {       // ~3 iterations
        const int e = eb + i;
        const int d = dst[e];
        const unsigned b = (unsigned)d >> 8;
        const unsigned pos = atomicAdd(&lcur[b], 1u);
        const int   s = src[e];
        const float w = weight[e];
        if (pos < SLICE_CAP) {
            ebuf[(size_t)(b * 256 + bi) * SLICE_CAP + pos] =
                make_uint2((unsigned)s | ((unsigned)(d & 255) << 16),
                           __float_as_uint(w));
        } else {                                  // slice overflow (P ~ 1e-18)
            const unsigned sp = atomicAdd(&lsp, 1u);
            if (sp < SPB)
                spillbuf[bi * SPB + sp] =
                    make_uint2((unsigned)s | ((unsigned)d << 16),
                               __float_as_uint(w));
        }
    }
    __syncthreads();
    if (tid < NBUCK) hcnt[tid * 256 + bi] = lcur[tid];   // hcnt[b][bi]
    if (tid == 0) scnt[bi] = lsp;

    // Fused queue fp32 -> fp16 convert (~4 iterations, streaming).
    const int gid = bi * 1024 + tid;              // 262144 threads
    for (int t = gid; t < N_NODES * D_FEAT / 4; t += BIN_BLOCKS * 1024) {
        const float4 q = reinterpret_cast<const float4*>(queue)[t];
        ushort4 h;
        h.x = __half_as_ushort(__float2half(q.x));
        h.y = __half_as_ushort(__float2half(q.y));
        h.z = __half_as_ushort(__float2half(q.z));
        h.w = __half_as_ushort(__float2half(q.w));
        reinterpret_cast<ushort4*>(qh)[t] = h;
    }
}

// Pass 2 (fused csr+pull): one block per bucket; CSR built in LDS, pulled
// in place. Wave w handles nodes w*16..w*16+15 of the bucket.
__global__ void __launch_bounds__(1024)
gather_kernel(const uint2* __restrict__ ebuf, const unsigned* __restrict__ hcnt,
              const unsigned* __restrict__ scnt, const uint2* __restrict__ spillbuf,
              const __half* __restrict__ qh, const float* __restrict__ queue,
              float* __restrict__ out) {
    __shared__ unsigned lcnt[256];
    __shared__ unsigned csr_l[256 * CAP];         // 32 KB
    __shared__ uint2    oflow[OFC];               // deg>32 excess (fp32 path)
    __shared__ unsigned ocnt;
    const int b   = blockIdx.x;                   // bucket 0..195
    const int tid = threadIdx.x;
    if (tid < 256) lcnt[tid] = 0;
    if (tid == 0) ocnt = 0;
    __syncthreads();

    // Phase 1: drain the bucket's 256 slices into the LDS CSR.
    {
        const int slice = tid >> 2, sub = tid & 3;       // 4 threads/slice
        const int hb = min((int)hcnt[b * 256 + slice], SLICE_CAP);
        const uint2* sl = ebuf + (size_t)(b * 256 + slice) * SLICE_CAP;
        for (int j = sub; j < hb; j += 4) {              // ~4 iterations
            const uint2 u = sl[j];
            const unsigned nlo = u.x >> 16;
            const unsigned pos = atomicAdd(&lcnt[nlo], 1u);
            if (pos < CAP) {
                csr_l[nlo * CAP + pos] =
                    pack_entry(u.x & 0xffffu, __uint_as_float(u.y));
            } else {                              // deg > 32: exact fp32 path
                const unsigned o = atomicAdd(&ocnt, 1u);
                if (o < OFC)
                    oflow[o] = make_uint2((u.x & 0xffffu) |
                                          ((((unsigned)b << 8) + nlo) << 16), u.y);
            }
        }
    }
    // Phase 1.5: import global slice-overflow spills for this bucket (~none).
    if (tid < 256) {
        const int sc = min((int)scnt[tid], SPB);
        for (int j = 0; j < sc; ++j) {
            const uint2 u = spillbuf[tid * SPB + j];
            if ((u.x >> 16) >> 8 == (unsigned)b) {
                const unsigned o = atomicAdd(&ocnt, 1u);
                if (o < OFC) oflow[o] = u;
            }
        }
    }
    __syncthreads();

    // Phase 2: pull. 16 waves x 16 nodes.
    const int wv = tid >> 6, lane = tid & 63;
    const int g = lane >> 3;                      // edge group 0..7
    const int k = lane & 7;                       // 16B chunk within 128B row
    const unsigned oc = min(ocnt, (unsigned)OFC);

    for (int q = 0; q < 16; ++q) {
        const int nlo = wv * 16 + q;
        const unsigned node = ((unsigned)b << 8) + (unsigned)nlo;
        if (node >= N_NODES) break;               // bucket 195 tail only
        const int c = min((int)lcnt[nlo], CAP);

        float a0 = 0, a1 = 0, a2 = 0, a3 = 0, a4 = 0, a5 = 0, a6 = 0, a7 = 0;
#pragma unroll
        for (int it = 0; it < 4; ++it) {
            if (it * 8 < c) {                     // wave-uniform tier skip
                const int slot = g + it * 8;
                unsigned e = csr_l[nlo * CAP + slot];    // 8-lane broadcast
                if (slot >= c) e = 0u;            // masked: src=0, w=fp16(0)
                const float w = entry_w(e);
                const uvec4 r = *reinterpret_cast<const uvec4*>(
                    qh + (size_t)(e >> 16) * D_FEAT + k * 8);
                const float2 f0 = h2f2(r.x), f1 = h2f2(r.y),
                             f2 = h2f2(r.z), f3 = h2f2(r.w);
                a0 = fmaf(f0.x, w, a0);  a1 = fmaf(f0.y, w, a1);
                a2 = fmaf(f1.x, w, a2);  a3 = fmaf(f1.y, w, a3);
                a4 = fmaf(f2.x, w, a4);  a5 = fmaf(f2.y, w, a5);
                a6 = fmaf(f3.x, w, a6);  a7 = fmaf(f3.y, w, a7);
            }
        }
#pragma unroll
        for (int m = 8; m <= 32; m <<= 1) {       // cross-group reduce
            a0 += __shfl_xor(a0, m);  a1 += __shfl_xor(a1, m);
            a2 += __shfl_xor(a2, m);  a3 += __shfl_xor(a3, m);
            a4 += __shfl_xor(a4, m);  a5 += __shfl_xor(a5, m);
            a6 += __shfl_xor(a6, m);  a7 += __shfl_xor(a7, m);
        }
        if (oc > 0 && lane < 8) {                 // overflow edges (fp32, rare)
            for (unsigned o = 0; o < oc; ++o) {
                const uint2 u = oflow[o];
                if ((u.x >> 16) == node) {
                    const float w = __uint_as_float(u.y);
                    const float* qr = queue + (size_t)(u.x & 0xffffu) * D_FEAT + lane * 8;
                    a0 = fmaf(qr[0], w, a0);  a1 = fmaf(qr[1], w, a1);
                    a2 = fmaf(qr[2], w, a2);  a3 = fmaf(qr[3], w, a3);
                    a4 = fmaf(qr[4], w, a4);  a5 = fmaf(qr[5], w, a5);
                    a6 = fmaf(qr[6], w, a6);  a7 = fmaf(qr[7], w, a7);
                }
            }
        }
        if (lane < 8) {                           // 8 lanes x 32B = 256B row
            float* o = out + (size_t)node * D_FEAT + lane * 8;
            *reinterpret_cast<float4*>(o)     = make_float4(a0, a1, a2, a3);
            *reinterpret_cast<float4*>(o + 4) = make_float4(a4, a5, a6, a7);
        }
    }
}

// --- Fallback (round-1 scatter) if ws_size is ever too small ---------------
__global__ void __launch_bounds__(256)
scatter_add_kernel(const float* __restrict__ queue,
                   const float* __restrict__ weight,
                   const int* __restrict__ src,
                   const int* __restrict__ dst,
                   float* __restrict__ out) {
    long long tid = (long long)blockIdx.x * blockDim.x + threadIdx.x;
    int e = (int)(tid >> 4);
    int c = ((int)tid & 15) << 2;
    if (e >= N_EDGES) return;
    int s = src[e], d = dst[e];
    float w = weight[e];
    const float4 q = *reinterpret_cast<const float4*>(queue + (size_t)s * D_FEAT + c);
    float* o = out + (size_t)d * D_FEAT + c;
    atomicAdd(o + 0, q.x * w);
    atomicAdd(o + 1, q.y * w);
    atomicAdd(o + 2, q.z * w);
    atomicAdd(o + 3, q.w * w);
}

extern "C" void kernel_launch(void* const* d_in, const int* in_sizes, int n_in,
                              void* d_out, int out_size, void* d_ws, size_t ws_size,
                              hipStream_t stream) {
    const float* queue  = (const float*)d_in[0];
    const float* weight = (const float*)d_in[1];
    const int*   src    = (const int*)d_in[2];
    const int*   dst    = (const int*)d_in[3];
    float* out = (float*)d_out;

    // Workspace layout (16B-aligned blocks). Nothing needs pre-zeroing:
    //   qh:       N_NODES*D_FEAT __half          (6.4 MB)
    //   ebuf:     NBUCK*256*SLICE_CAP uint2      (25.7 MB)
    //   spillbuf: 256*SPB uint2                  (512 KB)
    //   hcnt:     NBUCK*256 unsigned             (200 KB, written every call)
    //   scnt:     256 unsigned                   (written every call)
    const size_t qh_bytes    = (size_t)N_NODES * D_FEAT * sizeof(__half);
    const size_t ebuf_bytes  = (size_t)NBUCK * 256 * SLICE_CAP * sizeof(uint2);
    const size_t spill_bytes = (size_t)256 * SPB * sizeof(uint2);
    const size_t hcnt_bytes  = (size_t)NBUCK * 256 * sizeof(unsigned);
    const size_t need = qh_bytes + ebuf_bytes + spill_bytes + hcnt_bytes
                      + 256 * sizeof(unsigned);

    if (ws_size < need) {  // safety fallback: round-1 scatter path
        hipMemsetAsync(out, 0, (size_t)out_size * sizeof(float), stream);
        const long long total = (long long)N_EDGES * 16;
        scatter_add_kernel<<<(int)((total + 255) / 256), 256, 0, stream>>>(
            queue, weight, src, dst, out);
        return;
    }

    char* ws = (char*)d_ws;
    __half*   qh       = (__half*)ws;
    uint2*    ebuf     = (uint2*)(ws + qh_bytes);
    uint2*    spillbuf = (uint2*)(ws + qh_bytes + ebuf_bytes);
    unsigned* hcnt     = (unsigned*)(ws + qh_bytes + ebuf_bytes + spill_bytes);
    unsigned* scnt     = hcnt + NBUCK * 256;

    bin_kernel<<<BIN_BLOCKS, 1024, 0, stream>>>(
        src, dst, weight, queue, ebuf, hcnt, scnt, spillbuf, qh);
    gather_kernel<<<NBUCK, 1024, 0, stream>>>(
        ebuf, hcnt, scnt, spillbuf, qh, queue, out);
}